// Round 9
// baseline (63.447 us; speedup 1.0000x reference)
//
#include <hip/hip_runtime.h>
#include <hip/hip_bf16.h>

// Conv2d: B=16, CIN=128, COUT=256, H=W=56, 3x3, stride1, pad1, fp32, + bias.
// Implicit GEMM, bf16 MFMA. M=256(co), N=16*56*64=57344(px, W padded 64), K=1152.
// R9: m97-faithful. 128x128 tile, BK=32, double-buffered 2x16KB LDS (32KB total
// -> 4-5 blocks/CU residency AND in-block prefetch). Per K-tile: 4 gll16 (stage
// kt+1), 8 ds_read_b128, 16 MFMA, ONE __syncthreads. 64B-row swizzle
// byte(r,k)=r*64+((k>>3)^(r&3))*16+(k&7)*2 (lane-enumerated conflict-free);
// inverse swizzle folded into wtrans + per-lane B global sources. XCD swizzle (T1).

#define XT_BYTES   15204352u   // 16*58*64*128*2
#define SLACK      8192u
#define WT_OFFSET  (XT_BYTES + SLACK)
#define WT_BYTES   589824u     // 36 kt * 2 pm * 8KB
#define WS_NEED    (WT_OFFSET + WT_BYTES)

typedef __bf16 bf16x8 __attribute__((ext_vector_type(8)));
typedef float  f32x4  __attribute__((ext_vector_type(4)));
typedef unsigned short ushort8v __attribute__((ext_vector_type(8)));

__device__ __forceinline__ unsigned short f2bf(float f) {
  unsigned u = __builtin_bit_cast(unsigned, f);
  u += 0x7fffu + ((u >> 16) & 1u);
  return (unsigned short)(u >> 16);
}

__device__ __forceinline__ void gll16(const void* g, const void* l) {
  __builtin_amdgcn_global_load_lds(
      (const __attribute__((address_space(1))) unsigned int*)g,
      (__attribute__((address_space(3))) unsigned int*)l, 16, 0, 0);
}

// ---------------- fused prep kernel ----------------
// blocks 0..895: xtrans for (b,h) + zero pad-cols of that row
// blocks 896..927: zero rows 0 / 57 per image
// blocks 928..945: wtrans old-k64 tile -> two BK=32 tiles, pre-swizzled slots
__global__ void prep(const float* __restrict__ x, const float* __restrict__ wsrc,
                     unsigned short* __restrict__ xt, unsigned short* __restrict__ wt) {
  int blk = blockIdx.x;
  int t = threadIdx.x;   // 256
  if (blk < 896) {
    __shared__ unsigned short tile[128][58];
    int b = blk / 56, h = blk % 56;
    int ci = t >> 1, half = t & 1;
    const float* src = x + ((size_t)(b * 128 + ci)) * 3136 + h * 56 + half * 28;
    #pragma unroll
    for (int q = 0; q < 7; ++q) {
      float4 v = *(const float4*)&src[q * 4];
      int wb = half * 28 + q * 4;
      tile[ci][wb + 0] = f2bf(v.x);
      tile[ci][wb + 1] = f2bf(v.y);
      tile[ci][wb + 2] = f2bf(v.z);
      tile[ci][wb + 3] = f2bf(v.w);
    }
    unsigned short* row = xt + (size_t)b * 475136 + (size_t)(h + 1) * 8192;
    if (t < 128) {  // zero pad cols 0, 57..63 of this padded row
      int slot = t >> 4;
      int px = slot ? 56 + slot : 0;
      uint4 z; z.x = z.y = z.z = z.w = 0u;
      *(uint4*)(row + px * 128 + (t & 15) * 8) = z;
    }
    __syncthreads();
    if (t < 224) {
      int wo = t >> 2, chunk = t & 3;
      unsigned short* dst = row + (size_t)(wo + 1) * 128 + chunk * 32;
      #pragma unroll
      for (int q = 0; q < 4; ++q) {
        ushort8v v;
        #pragma unroll
        for (int j = 0; j < 8; ++j) v[j] = tile[chunk * 32 + q * 8 + j][wo];
        *(ushort8v*)&dst[q * 8] = v;
      }
    }
  } else if (blk < 928) {
    int idx = blk - 896;
    int b = idx >> 1, zr = (idx & 1) ? 57 : 0;
    uint4* dst = (uint4*)(xt + (size_t)b * 475136 + (size_t)zr * 8192);
    uint4 z; z.x = z.y = z.z = z.w = 0u;
    #pragma unroll
    for (int q = 0; q < 4; ++q) dst[t + q * 256] = z;
  } else {
    int k64 = blk - 928;         // 0..17
    int tap = k64 >> 1;
    int ci_base = (k64 & 1) * 64;
    #pragma unroll
    for (int h = 0; h < 2; ++h) {
      int kt = k64 * 2 + h;      // BK=32 tile index, 0..35
      int ci0 = ci_base + h * 32;
      #pragma unroll
      for (int pm = 0; pm < 2; ++pm) {
        #pragma unroll
        for (int q = 0; q < 2; ++q) {
          int n = t + q * 256;   // 0..511
          int r = n >> 2, s = n & 3;
          int kg = s ^ (r & 3);
          int co = pm * 128 + r;
          const float* src = wsrc + (size_t)co * 1152 + (size_t)(ci0 + kg * 8) * 9 + tap;
          ushort8v v;
          #pragma unroll
          for (int j = 0; j < 8; ++j) v[j] = f2bf(src[j * 9]);
          *(ushort8v*)&wt[((size_t)kt * 2 + pm) * 4096 + n * 8] = v;
        }
      }
    }
  }
}

// ---------------- main GEMM kernel ----------------
// LDS buffer (16KB): A [128co][32k] at +0, B [128px][32k] at +8192. Two buffers.
// swizzle: byte(r,k) = r*64 + ((k>>3) ^ (r&3))*16 + (k&7)*2

__global__ __launch_bounds__(256, 5) void conv_gemm(
    const unsigned short* __restrict__ xt,
    const char* __restrict__ wt,
    const float* __restrict__ bias,
    float* __restrict__ out) {
  __shared__ __align__(16) char lds[32768];    // 2 x 16KB

  int bid = blockIdx.x;
  int sw = (bid & 7) * 112 + (bid >> 3);       // XCD swizzle, 896 = 8*112
  int pm = sw & 1;                             // co half
  int pn = sw >> 1;                            // 0..447 pixel tile
  int bimg = pn / 28;
  int h0 = (pn - bimg * 28) * 2;               // 2 output rows per tile

  int tid = threadIdx.x;
  int wv = tid >> 6, l = tid & 63;
  int wm = wv >> 1, wn = wv & 1;               // 2M x 2N waves, 64x64 each
  int lm = l & 15, lg = l >> 4;
  int swz = ((lg ^ (lm & 3)) << 4);

  int aoff0 = wm * 4096 + lm * 64 + swz;
  int boff0 = 8192 + wn * 4096 + lm * 64 + swz;

  // staging sources (LDS dest linear; inverse swizzle folded into source)
  const char* aB = wt + pm * 8192 + (wv * 64 + l) * 16;
  const unsigned short* bB[2];
  #pragma unroll
  for (int j = 0; j < 2; ++j) {
    int n = wv * 64 + l + j * 256;             // 0..511
    int px = n >> 2;                           // 0..127
    int kg = (n & 3) ^ (px & 3);
    bB[j] = xt + ((size_t)((bimg * 58 + h0 + (px >> 6)) * 64 + (px & 63))) * 128 + kg * 8;
  }

  f32x4 acc[4][4];
  #pragma unroll
  for (int m = 0; m < 4; ++m)
    #pragma unroll
    for (int n = 0; n < 4; ++n)
      acc[m][n] = (f32x4){0.f, 0.f, 0.f, 0.f};

  auto stage = [&](int kt, int buf) {
    int tap = kt >> 2;
    int kh = tap >= 6 ? 2 : (tap >= 3 ? 1 : 0);
    int kw = tap - kh * 3;
    int koff = (kh * 64 + kw) * 128 + (kt & 3) * 32;   // ushort units
    const char* sA = aB + kt * 16384;
    char* dA = &lds[buf * 16384 + (wv * 64 + l) * 16];
    char* dB = dA + 8192;
    gll16(sA, dA);
    gll16(sA + 4096, dA + 4096);
    gll16(bB[0] + koff, dB);
    gll16(bB[1] + koff, dB + 4096);
  };

  stage(0, 0);
  __syncthreads();

  for (int kt = 0; kt < 36; ++kt) {
    const char* base = &lds[(kt & 1) * 16384];
    if (kt < 35) stage(kt + 1, (kt + 1) & 1);   // prefetch next tile (other buffer)
    bf16x8 a[4], b[4];
    #pragma unroll
    for (int m = 0; m < 4; ++m) a[m] = *(const bf16x8*)(base + aoff0 + m * 1024);
    #pragma unroll
    for (int n = 0; n < 4; ++n) b[n] = *(const bf16x8*)(base + boff0 + n * 1024);
    #pragma unroll
    for (int m = 0; m < 4; ++m)
      #pragma unroll
      for (int n = 0; n < 4; ++n)
        acc[m][n] = __builtin_amdgcn_mfma_f32_16x16x32_bf16(a[m], b[n], acc[m][n], 0, 0, 0);
    if (kt < 35) __syncthreads();   // drain: kt+1 staged, reads of base done
  }

  // epilogue: bias + masked store (w' < 56)
  #pragma unroll
  for (int m = 0; m < 4; ++m) {
    int co = pm * 128 + wm * 64 + m * 16 + lg * 4;
    f32x4 bb = *(const f32x4*)&bias[co];
    size_t obase = ((size_t)bimg * 256 + co) * 3136;
    #pragma unroll
    for (int n = 0; n < 4; ++n) {
      int px = wn * 64 + n * 16 + lm;
      int w_ = px & 63;
      int h_ = h0 + (px >> 6);
      if (w_ < 56) {
        float* o = out + obase + (size_t)h_ * 56 + w_;
        #pragma unroll
        for (int r = 0; r < 4; ++r)
          o[(size_t)r * 3136] = acc[m][n][r] + bb[r];
      }
    }
  }
}

// ---------------- fallback (tiny ws) ----------------

__global__ void conv_naive(const float* __restrict__ x, const float* __restrict__ w,
                           const float* __restrict__ bias, float* __restrict__ out) {
  int idx = blockIdx.x * 256 + threadIdx.x;
  if (idx >= 16 * 256 * 56 * 56) return;
  int wo = idx % 56; int t = idx / 56;
  int ho = t % 56; t /= 56;
  int co = t % 256; int b = t / 256;
  float acc = bias[co];
  for (int ci = 0; ci < 128; ++ci) {
    const float* xp = x + ((size_t)(b * 128 + ci)) * 3136;
    const float* wp = w + ((size_t)(co * 128 + ci)) * 9;
    for (int kh = 0; kh < 3; ++kh) {
      int hi = ho + kh - 1;
      if (hi < 0 || hi >= 56) continue;
      for (int kw = 0; kw < 3; ++kw) {
        int wi = wo + kw - 1;
        if (wi < 0 || wi >= 56) continue;
        acc += xp[hi * 56 + wi] * wp[kh * 3 + kw];
      }
    }
  }
  out[idx] = acc;
}

extern "C" void kernel_launch(void* const* d_in, const int* in_sizes, int n_in,
                              void* d_out, int out_size, void* d_ws, size_t ws_size,
                              hipStream_t stream) {
  const float* x    = (const float*)d_in[0];
  const float* wgt  = (const float*)d_in[1];
  const float* bias = (const float*)d_in[2];
  float* out = (float*)d_out;

  if (ws_size < (size_t)WS_NEED) {
    conv_naive<<<(16 * 256 * 56 * 56 + 255) / 256, 256, 0, stream>>>(x, wgt, bias, out);
    return;
  }

  unsigned short* xt = (unsigned short*)d_ws;
  unsigned short* wt = (unsigned short*)((char*)d_ws + WT_OFFSET);

  prep<<<946, 256, 0, stream>>>(x, wgt, xt, wt);
  conv_gemm<<<896, 256, 0, stream>>>(xt, (const char*)wt, bias, out);
}

// Round 10
// 57.883 us; speedup vs baseline: 1.0961x; 1.0961x over previous
//
#include <hip/hip_runtime.h>
#include <hip/hip_bf16.h>

// Conv2d: B=16, CIN=128, COUT=256, H=W=56, 3x3, stride1, pad1, fp32, + bias.
// Implicit GEMM, bf16 MFMA. M=256(co), N=16*56*64=57344(px, W padded 64), K=1152.
// R10: 256x128 block, 4 waves of 128x64 (raises LDS-BW ceiling 60%->83%), BK=32,
// ring-3 LDS 72KB -> 2 blocks/CU, counted vmcnt(6) (never 0 until epilogue, T4),
// ONE raw s_barrier/tile. Swizzle: row r, pos p holds kgroup p^((r>>1)&3)
// (lane-enumerated bijective per 8-lane group). Inverse folded into prep (rule 21).

#define XT_BYTES   15204352u   // 16*58*64*128*2
#define SLACK      8192u
#define WT_OFFSET  (XT_BYTES + SLACK)
#define WT_BYTES   589824u     // 36 kt * 16KB
#define WS_NEED    (WT_OFFSET + WT_BYTES)

typedef __bf16 bf16x8 __attribute__((ext_vector_type(8)));
typedef float  f32x4  __attribute__((ext_vector_type(4)));
typedef unsigned short ushort8v __attribute__((ext_vector_type(8)));

#define BAR()   __builtin_amdgcn_s_barrier()
#define SB0()   __builtin_amdgcn_sched_barrier(0)

__device__ __forceinline__ unsigned short f2bf(float f) {
  unsigned u = __builtin_bit_cast(unsigned, f);
  u += 0x7fffu + ((u >> 16) & 1u);
  return (unsigned short)(u >> 16);
}

__device__ __forceinline__ void gll16(const void* g, const void* l) {
  __builtin_amdgcn_global_load_lds(
      (const __attribute__((address_space(1))) unsigned int*)g,
      (__attribute__((address_space(3))) unsigned int*)l, 16, 0, 0);
}

// ---------------- fused prep kernel ----------------
// blocks 0..895: xtrans (b,h) + pad cols; 896..927: pad rows; 928..945: wtrans.
// wtrans: wt[kt][slot n 0..1023]: co=n>>2, p=n&3, kg=p^((co>>1)&3),
//         holds bf16 w[co][ (kt&3)*32 + kg*8 .. +8 ][tap=kt>>2]
__global__ void prep(const float* __restrict__ x, const float* __restrict__ wsrc,
                     unsigned short* __restrict__ xt, unsigned short* __restrict__ wt) {
  int blk = blockIdx.x;
  int t = threadIdx.x;   // 256
  if (blk < 896) {
    __shared__ unsigned short tile[128][58];
    int b = blk / 56, h = blk % 56;
    int ci = t >> 1, half = t & 1;
    const float* src = x + ((size_t)(b * 128 + ci)) * 3136 + h * 56 + half * 28;
    #pragma unroll
    for (int q = 0; q < 7; ++q) {
      float4 v = *(const float4*)&src[q * 4];
      int wb = half * 28 + q * 4;
      tile[ci][wb + 0] = f2bf(v.x);
      tile[ci][wb + 1] = f2bf(v.y);
      tile[ci][wb + 2] = f2bf(v.z);
      tile[ci][wb + 3] = f2bf(v.w);
    }
    unsigned short* row = xt + (size_t)b * 475136 + (size_t)(h + 1) * 8192;
    if (t < 128) {
      int slot = t >> 4;
      int px = slot ? 56 + slot : 0;
      uint4 z; z.x = z.y = z.z = z.w = 0u;
      *(uint4*)(row + px * 128 + (t & 15) * 8) = z;
    }
    __syncthreads();
    if (t < 224) {
      int wo = t >> 2, chunk = t & 3;
      unsigned short* dst = row + (size_t)(wo + 1) * 128 + chunk * 32;
      #pragma unroll
      for (int q = 0; q < 4; ++q) {
        ushort8v v;
        #pragma unroll
        for (int j = 0; j < 8; ++j) v[j] = tile[chunk * 32 + q * 8 + j][wo];
        *(ushort8v*)&dst[q * 8] = v;
      }
    }
  } else if (blk < 928) {
    int idx = blk - 896;
    int b = idx >> 1, zr = (idx & 1) ? 57 : 0;
    uint4* dst = (uint4*)(xt + (size_t)b * 475136 + (size_t)zr * 8192);
    uint4 z; z.x = z.y = z.z = z.w = 0u;
    #pragma unroll
    for (int q = 0; q < 4; ++q) dst[t + q * 256] = z;
  } else {
    int base_kt = (blk - 928) * 2;   // 18 blocks x 2 kt = 36
    #pragma unroll
    for (int kk = 0; kk < 2; ++kk) {
      int kt = base_kt + kk;
      int tap = kt >> 2, ci0 = (kt & 3) * 32;
      #pragma unroll
      for (int q = 0; q < 4; ++q) {
        int n = t + q * 256;       // 0..1023
        int co = n >> 2, p = n & 3;
        int kg = p ^ ((co >> 1) & 3);
        const float* src = wsrc + (size_t)co * 1152 + (size_t)(ci0 + kg * 8) * 9 + tap;
        ushort8v v;
        #pragma unroll
        for (int j = 0; j < 8; ++j) v[j] = f2bf(src[j * 9]);
        *(ushort8v*)&wt[(size_t)kt * 8192 + n * 8] = v;
      }
    }
  }
}

// ---------------- main GEMM kernel ----------------
// LDS per buffer (24KB): A [256co][32k] @0 (64B rows), B [128px][32k] @16384.
// Row r holds its 4 k-groups at pos p with kg = p ^ ((r>>1)&3).

__global__ __launch_bounds__(256, 2) void conv_gemm(
    const unsigned short* __restrict__ xt,
    const char* __restrict__ wt,
    const float* __restrict__ bias,
    float* __restrict__ out) {
  __shared__ __align__(16) char lds[73728];    // 3 x 24KB ring

  int bid = blockIdx.x;
  int sw = (bid & 7) * 56 + (bid >> 3);        // XCD swizzle, 448 = 8*56
  int bimg = sw / 28;
  int h0 = (sw - bimg * 28) * 2;               // 2 output rows (64px each)

  int tid = threadIdx.x;
  int wv = tid >> 6, l = tid & 63;
  int wm = wv >> 1, wn = wv & 1;               // 2M x 2N waves, 128x64 each
  int lm = l & 15, lg = l >> 4;

  // fragment read byte offsets (conflict-free by construction)
  int aRd[8], bRd[4];
  #pragma unroll
  for (int m = 0; m < 8; ++m) {
    int row = wm * 128 + m * 16 + lm;
    aRd[m] = row * 64 + ((lg ^ ((row >> 1) & 3)) << 4);
  }
  #pragma unroll
  for (int n = 0; n < 4; ++n) {
    int row = wn * 64 + n * 16 + lm;
    bRd[n] = 16384 + row * 64 + ((lg ^ ((row >> 1) & 3)) << 4);
  }

  // staging sources (LDS dest linear; inverse swizzle folded into source)
  const char* aS = wt + tid * 16;              // + kt*16384 + q*4096
  const unsigned short* bS[2];
  #pragma unroll
  for (int j = 0; j < 2; ++j) {
    int n = tid + j * 256;                     // 0..511
    int px = n >> 2, p = n & 3;
    int kg = p ^ ((px >> 1) & 3);
    bS[j] = xt + ((size_t)((bimg * 58 + h0 + (px >> 6)) * 64 + (px & 63))) * 128 + kg * 8;
  }

  f32x4 acc[8][4];
  #pragma unroll
  for (int m = 0; m < 8; ++m)
    #pragma unroll
    for (int n = 0; n < 4; ++n)
      acc[m][n] = (f32x4){0.f, 0.f, 0.f, 0.f};

  auto stage = [&](int kt, int buf) {
    int tap = kt >> 2;
    int kh = tap >= 6 ? 2 : (tap >= 3 ? 1 : 0);
    int kw = tap - kh * 3;
    int koff = (kh * 64 + kw) * 128 + (kt & 3) * 32;   // ushort units
    const char* sA = aS + kt * 16384;
    char* d = &lds[buf * 24576 + tid * 16];
    #pragma unroll
    for (int q = 0; q < 4; ++q) gll16(sA + q * 4096, d + q * 4096);
    char* dB = &lds[buf * 24576 + 16384 + tid * 16];
    gll16(bS[0] + koff, dB);
    gll16(bS[1] + koff, dB + 4096);
  };

  // prologue: stage kt0->buf0, kt1->buf1; retire kt0's 6, keep kt1's 6 in flight
  stage(0, 0);
  stage(1, 1);
  asm volatile("s_waitcnt vmcnt(6)" ::: "memory");
  SB0(); BAR(); SB0();

  int cb = 0;
  for (int kt = 0; kt < 36; ++kt) {
    int nb = cb >= 1 ? cb - 1 : 2;             // (cb+2)%3
    if (kt < 34) stage(kt + 2, nb);            // post-barrier: WAR-safe overwrite
    const char* base = &lds[cb * 24576];
    bf16x8 a[8], b[4];
    #pragma unroll
    for (int m = 0; m < 8; ++m) a[m] = *(const bf16x8*)(base + aRd[m]);
    #pragma unroll
    for (int n = 0; n < 4; ++n) b[n] = *(const bf16x8*)(base + bRd[n]);
    #pragma unroll
    for (int m = 0; m < 8; ++m)
      #pragma unroll
      for (int n = 0; n < 4; ++n)
        acc[m][n] = __builtin_amdgcn_mfma_f32_16x16x32_bf16(a[m], b[n], acc[m][n], 0, 0, 0);
    // counted vmcnt: retire kt+1's 6 loads; keep kt+2's 6 in flight (T4)
    if (kt < 34)       asm volatile("s_waitcnt vmcnt(6)" ::: "memory");
    else if (kt == 34) asm volatile("s_waitcnt vmcnt(0)" ::: "memory");
    SB0(); BAR(); SB0();
    cb = cb == 2 ? 0 : cb + 1;
  }

  // epilogue: bias + masked store (w' < 56)
  #pragma unroll
  for (int m = 0; m < 8; ++m) {
    int co = wm * 128 + m * 16 + lg * 4;
    f32x4 bb = *(const f32x4*)&bias[co];
    size_t obase = ((size_t)bimg * 256 + co) * 3136;
    #pragma unroll
    for (int n = 0; n < 4; ++n) {
      int px = wn * 64 + n * 16 + lm;
      int w_ = px & 63;
      int h_ = h0 + (px >> 6);
      if (w_ < 56) {
        float* o = out + obase + (size_t)h_ * 56 + w_;
        #pragma unroll
        for (int r = 0; r < 4; ++r)
          o[(size_t)r * 3136] = acc[m][n][r] + bb[r];
      }
    }
  }
}

// ---------------- fallback (tiny ws) ----------------

__global__ void conv_naive(const float* __restrict__ x, const float* __restrict__ w,
                           const float* __restrict__ bias, float* __restrict__ out) {
  int idx = blockIdx.x * 256 + threadIdx.x;
  if (idx >= 16 * 256 * 56 * 56) return;
  int wo = idx % 56; int t = idx / 56;
  int ho = t % 56; t /= 56;
  int co = t % 256; int b = t / 256;
  float acc = bias[co];
  for (int ci = 0; ci < 128; ++ci) {
    const float* xp = x + ((size_t)(b * 128 + ci)) * 3136;
    const float* wp = w + ((size_t)(co * 128 + ci)) * 9;
    for (int kh = 0; kh < 3; ++kh) {
      int hi = ho + kh - 1;
      if (hi < 0 || hi >= 56) continue;
      for (int kw = 0; kw < 3; ++kw) {
        int wi = wo + kw - 1;
        if (wi < 0 || wi >= 56) continue;
        acc += xp[hi * 56 + wi] * wp[kh * 3 + kw];
      }
    }
  }
  out[idx] = acc;
}

extern "C" void kernel_launch(void* const* d_in, const int* in_sizes, int n_in,
                              void* d_out, int out_size, void* d_ws, size_t ws_size,
                              hipStream_t stream) {
  const float* x    = (const float*)d_in[0];
  const float* wgt  = (const float*)d_in[1];
  const float* bias = (const float*)d_in[2];
  float* out = (float*)d_out;

  if (ws_size < (size_t)WS_NEED) {
    conv_naive<<<(16 * 256 * 56 * 56 + 255) / 256, 256, 0, stream>>>(x, wgt, bias, out);
    return;
  }

  unsigned short* xt = (unsigned short*)d_ws;
  unsigned short* wt = (unsigned short*)((char*)d_ws + WT_OFFSET);

  prep<<<946, 256, 0, stream>>>(x, wgt, xt, wt);
  conv_gemm<<<448, 256, 0, stream>>>(xt, (const char*)wt, bias, out);
}